// Round 4
// baseline (633.194 us; speedup 1.0000x reference)
//
#include <hip/hip_runtime.h>

#define NUMA 5
#define NCLS 80
#define AL 85          // 80 + 4 + 1
#define HW 361         // 19*19
#define NBOX 1805      // 5*361
#define NBATCH 128
#define NPAD 2048
#define K2T 256
#define MCAP 1024      // register-path cap on num_obj (expected ~902 +/- 21)
#define NCHUNK 16      // MCAP / 64

// ---- d_ws layout (phase-split path) ----
#define WS_NUMOBJ_OFF 0                                  // int32 [128]
#define WS_ORDER_OFF  512                                // u16   [128][2048]
#define WS_SOBJ_OFF   (512 + NBATCH * NPAD * 2)          // f32   [128][2048]
#define WS_NEEDED     ((size_t)(WS_SOBJ_OFF + NBATCH * NPAD * 4))   // ~1.5 MB

// ---------------------------------------------------------------------------
// Kernel 1: decode.  pred [B, 425, 19, 19] -> det [B, 1805, 7] written to out
// ---------------------------------------------------------------------------
__global__ __launch_bounds__(256) void decode_kernel(
    const float* __restrict__ pred,
    const float* __restrict__ anchors,
    float* __restrict__ det)
{
#pragma clang fp contract(off)
    int id = blockIdx.x * blockDim.x + threadIdx.x;
    if (id >= NBATCH * NBOX) return;
    int b = id / NBOX;
    int r = id - b * NBOX;
    int a = r / HW;
    int s = r - a * HW;
    int ci = s % 19;
    int cj = s / 19;

    const float* base = pred + ((size_t)(b * (NUMA * AL) + a * AL) * HW + s);
    float tx  = base[0 * HW];
    float ty  = base[1 * HW];
    float tw  = base[2 * HW];
    float th  = base[3 * HW];
    float obj = base[4 * HW];

    float cmax = base[5 * HW];
    int karg = 0;
#pragma unroll 4
    for (int k = 1; k < NCLS; ++k) {
        float c = base[(5 + k) * HW];
        if (c > cmax) { cmax = c; karg = k; }
    }

    float bx = (tx + (float)ci) / 19.0f;
    float by = (ty + (float)cj) / 19.0f;
    float aw = anchors[2 * a];
    float ah = anchors[2 * a + 1];
    float bw = expf(tw) * (aw / 19.0f);
    float bh = expf(th) * (ah / 19.0f);
    float prob = cmax * obj;
    float cid  = (float)karg;

    float* o = det + (size_t)(b * NBOX + r) * 7;
    o[0] = obj; o[1] = bx; o[2] = by; o[3] = bw; o[4] = bh; o[5] = cid; o[6] = prob;
}

// ---------------------------------------------------------------------------
// Kernel 2: per-image stable bitonic sort (desc by obj). 1024 threads/image.
// Writes order[2048] (u16), sorted obj[2048] (f32), num_obj (i32) to ws.
// ---------------------------------------------------------------------------
__global__ __launch_bounds__(1024) void sort_kernel(
    const float* __restrict__ det,
    unsigned short* __restrict__ order_g,
    float* __restrict__ sobj_g,
    int* __restrict__ nobj_g)
{
    __shared__ unsigned long long keys[NPAD];
    __shared__ int cnt_sh;
    const int b = blockIdx.x;
    const int tid = threadIdx.x;
    const float* detb = det + (size_t)b * NBOX * 7;

    for (int n = tid; n < NPAD; n += 1024) {
        keys[n] = (n < NBOX)
            ? (((unsigned long long)__float_as_uint(detb[n * 7]) << 32)
               | (unsigned long long)(2047 - n))
            : 0ull;
    }
    if (tid == 0) cnt_sh = 0;
    __syncthreads();

    for (unsigned k = 2; k <= NPAD; k <<= 1) {
        for (unsigned j = k >> 1; j > 0; j >>= 1) {
            for (unsigned idx = tid; idx < NPAD; idx += 1024) {
                unsigned ixj = idx ^ j;
                if (ixj > idx) {
                    unsigned long long av = keys[idx], bv = keys[ixj];
                    bool up = ((idx & k) == 0);
                    if (up ? (av < bv) : (av > bv)) { keys[idx] = bv; keys[ixj] = av; }
                }
            }
            __syncthreads();
        }
    }

    int cnt = 0;
    for (int r = tid; r < NBOX; r += 1024) {
        unsigned long long kk = keys[r];
        order_g[b * NPAD + r] = (unsigned short)(2047u - (unsigned)(kk & 0xffffffffu));
        float ob = __uint_as_float((unsigned)(kk >> 32));
        sobj_g[b * NPAD + r] = ob;
        cnt += (ob > 0.5f) ? 1 : 0;
    }
    atomicAdd(&cnt_sh, cnt);
    __syncthreads();
    if (tid == 0) nobj_g[b] = cnt_sh;
}

// ---------------------------------------------------------------------------
// Kernel 3: greedy NMS. ONE wave (64 threads) per image. Boxes in LDS; the
// only per-lane state is rm_bits (u32) -> no arrays, no scratch possible.
// Zeroes suppressed entries of sobj_g.
// ---------------------------------------------------------------------------
__global__ __launch_bounds__(64, 1) void nms3_kernel(
    const float* __restrict__ det,
    const unsigned short* __restrict__ order_g,
    float* __restrict__ sobj_g,
    const int* __restrict__ nobj_g)
{
#pragma clang fp contract(off)
    __shared__ float4 Qs[MCAP];   // (x1,y1,x2,y2) per sorted rank
    __shared__ float  As[MCAP];
    const int b = blockIdx.x;
    const int lane = threadIdx.x;
    const float* detb = det + (size_t)b * NBOX * 7;
    const unsigned short* ord = order_g + b * NPAD;
    float* sobj = sobj_g + b * NPAD;
    const int num_obj = nobj_g[b];
    const int M = (num_obj < MCAP) ? num_obj : MCAP;

    if (num_obj <= MCAP) {
        // gather boxes into LDS (pad with far-away sentinels)
        for (int r = lane; r < MCAP; r += 64) {
            if (r < M) {
                const float* row = detb + (int)ord[r] * 7;
                float bx = row[1], by = row[2], bw = row[3], bh = row[4];
                Qs[r] = make_float4(bx - 0.5f * bw, by - 0.5f * bh,
                                    bx + 0.5f * bw, by + 0.5f * bh);
                As[r] = bw * bh;
            } else {
                Qs[r] = make_float4(3e9f, 3e9f, 3e9f, 3e9f);
                As[r] = 1.0f;
            }
        }
        __syncthreads();

        unsigned rm_bits = 0u;    // bit c = this lane's box in chunk c removed
        for (int cchunk = 0; cchunk * 64 < M; ++cchunk) {
            const int cbase = cchunk * 64;
            unsigned long long chunkmask =
                (M - cbase >= 64) ? ~0ull : ((1ull << (M - cbase)) - 1ull);
            unsigned long long wc = __ballot((rm_bits >> cchunk) & 1u);
            unsigned long long done = 0ull;
            while (true) {
                unsigned long long avail = chunkmask & ~wc & ~done;
                if (avail == 0ull) break;
                int t = (int)__builtin_ctzll(avail);      // next alive rank in chunk
                done |= (t >= 63) ? ~0ull : ((1ull << (t + 1)) - 1ull);
                float4 qi = Qs[cbase + t];                // LDS broadcast
                float  ai = As[cbase + t];
#pragma unroll
                for (int c2 = 0; c2 < NCHUNK; ++c2) {
                    if (c2 >= cchunk && c2 * 64 < M) {    // wave-uniform guards
                        float4 qj = Qs[c2 * 64 + lane];
                        float  aj = As[c2 * 64 + lane];
                        float iw = fmaxf(fminf(qj.z, qi.z) - fmaxf(qj.x, qi.x), 0.0f);
                        float ih = fmaxf(fminf(qj.w, qi.w) - fmaxf(qj.y, qi.y), 0.0f);
                        float inter = iw * ih;
                        float iou = inter / ((aj + ai) - inter);   // exact ref arith
                        bool supp = (iou >= 0.45f) && ((c2 > cchunk) || (lane > t));
                        rm_bits |= supp ? (1u << c2) : 0u;
                        if (c2 == cchunk) wc |= __ballot(supp);
                    }
                }
            }
        }
        // write removals
#pragma unroll
        for (int c2 = 0; c2 < NCHUNK; ++c2) {
            int j = c2 * 64 + lane;
            if (j < M && ((rm_bits >> c2) & 1u)) sobj[j] = 0.0f;
        }
    } else {
        // fallback (num_obj > 1024; statistically unreachable): serial greedy
        for (int i = 0; i < num_obj; ++i) {
            if (sobj[i] > 0.01f) {
                const float* ri = detb + (int)ord[i] * 7;
                float bxi = ri[1], byi = ri[2], bwi = ri[3], bhi = ri[4];
                float xi1 = bxi - 0.5f * bwi, xi2 = bxi + 0.5f * bwi;
                float yi1 = byi - 0.5f * bhi, yi2 = byi + 0.5f * bhi;
                float ai = bwi * bhi;
                for (int j = i + 1 + lane; j < num_obj; j += 64) {
                    const float* rj = detb + (int)ord[j] * 7;
                    float bxj = rj[1], byj = rj[2], bwj = rj[3], bhj = rj[4];
                    float x1j = bxj - 0.5f * bwj, x2j = bxj + 0.5f * bwj;
                    float y1j = byj - 0.5f * bhj, y2j = byj + 0.5f * bhj;
                    float aj = bwj * bhj;
                    float iw = fmaxf(fminf(x2j, xi2) - fmaxf(x1j, xi1), 0.0f);
                    float ih = fmaxf(fminf(y2j, yi2) - fmaxf(y1j, yi1), 0.0f);
                    float inter = iw * ih;
                    float iou = inter / ((aj + ai) - inter);
                    if (iou >= 0.45f) sobj[j] = 0.0f;
                }
            }
            __syncthreads();
        }
    }
}

// ---------------------------------------------------------------------------
// Kernel 4: epilogue. Gather rows in sorted order, apply filters, write det
// in place (all reads before barrier, all writes after).
// ---------------------------------------------------------------------------
__global__ __launch_bounds__(256) void epi_kernel(
    float* __restrict__ det,
    const unsigned short* __restrict__ order_g,
    const float* __restrict__ sobj_g,
    const int* __restrict__ nobj_g)
{
#pragma clang fp contract(off)
    const int b = blockIdx.x;
    const int tid = threadIdx.x;
    float* detb = det + (size_t)b * NBOX * 7;
    const unsigned short* ord = order_g + b * NPAD;
    const float* sobj = sobj_g + b * NPAD;
    const int num_obj = nobj_g[b];

    float v0[8], v1[8], v2[8], v3[8], v4[8], v5[8], v6[8], msk[8];
#pragma unroll
    for (int c = 0; c < 8; ++c) {
        int r = tid + c * 256;
        if (r < NBOX) {
            const float* row = detb + (int)ord[r] * 7;
            float obj = row[0], bx = row[1], by = row[2], bw = row[3];
            float bh = row[4], cid = row[5], prob = row[6];
            bool keep = (r < num_obj) && (sobj[r] > 0.01f) && (r != num_obj - 1);
            float p = prob * ((prob > 0.1f) ? 1.0f : 0.0f);
            bool fin = keep && (p > 0.01f) && (bw * bw > 0.0004f);
            v0[c] = obj; v1[c] = bx; v2[c] = by; v3[c] = bw; v4[c] = bh;
            v5[c] = cid; v6[c] = p;
            msk[c] = fin ? 1.0f : 0.0f;
        }
    }
    __syncthreads();
#pragma unroll
    for (int c = 0; c < 8; ++c) {
        int r = tid + c * 256;
        if (r < NBOX) {
            float* o = detb + r * 7;
            o[0] = v0[c] * msk[c];
            o[1] = v1[c] * msk[c];
            o[2] = v2[c] * msk[c];
            o[3] = v3[c] * msk[c];
            o[4] = v4[c] * msk[c];
            o[5] = v5[c] * msk[c];
            o[6] = v6[c] * msk[c];
        }
    }
}

// ---------------------------------------------------------------------------
// Fallback monolithic kernel (used only if ws_size < WS_NEEDED): round-3
// version, known-correct.
// ---------------------------------------------------------------------------
__global__ __launch_bounds__(K2T, 1) void nms_kernel(float* __restrict__ det)
{
#pragma clang fp contract(off)
    __shared__ alignas(16) union {
        unsigned long long keys[NPAD];
        struct { float4 q[MCAP]; float area[MCAP]; } box;
    } U;
    __shared__ float s_obj[NBOX];
    __shared__ unsigned short order[NBOX];
    __shared__ int num_obj_sh;

    const int b = blockIdx.x;
    const int tid = threadIdx.x;
    float* detb = det + (size_t)b * NBOX * 7;

    for (int n = tid; n < NPAD; n += K2T) {
        if (n < NBOX) {
            unsigned ob = __float_as_uint(detb[n * 7 + 0]);
            U.keys[n] = ((unsigned long long)ob << 32) | (unsigned long long)(2047 - n);
        } else U.keys[n] = 0ull;
    }
    if (tid == 0) num_obj_sh = 0;
    __syncthreads();

    for (unsigned k = 2; k <= NPAD; k <<= 1) {
        for (unsigned j = k >> 1; j > 0; j >>= 1) {
            for (unsigned idx = tid; idx < NPAD; idx += K2T) {
                unsigned ixj = idx ^ j;
                if (ixj > idx) {
                    unsigned long long av = U.keys[idx], bv = U.keys[ixj];
                    bool up = ((idx & k) == 0);
                    if (up ? (av < bv) : (av > bv)) { U.keys[idx] = bv; U.keys[ixj] = av; }
                }
            }
            __syncthreads();
        }
    }

    int cnt = 0;
    for (int r = tid; r < NBOX; r += K2T) {
        unsigned long long kk = U.keys[r];
        order[r] = (unsigned short)(2047u - (unsigned)(kk & 0xffffffffu));
        float ob = __uint_as_float((unsigned)(kk >> 32));
        s_obj[r] = ob;
        cnt += (ob > 0.5f) ? 1 : 0;
    }
    atomicAdd(&num_obj_sh, cnt);
    __syncthreads();
    const int num_obj = num_obj_sh;

    for (int i = 0; i < num_obj; ++i) {
        if (s_obj[i] > 0.01f) {
            const float* ri = detb + (int)order[i] * 7;
            float bxi = ri[1], byi = ri[2], bwi = ri[3], bhi = ri[4];
            float xi1 = bxi - 0.5f * bwi, xi2 = bxi + 0.5f * bwi;
            float yi1 = byi - 0.5f * bhi, yi2 = byi + 0.5f * bhi;
            float ai = bwi * bhi;
            for (int j = i + 1 + tid; j < num_obj; j += K2T) {
                const float* rj = detb + (int)order[j] * 7;
                float bxj = rj[1], byj = rj[2], bwj = rj[3], bhj = rj[4];
                float x1j = bxj - 0.5f * bwj, x2j = bxj + 0.5f * bwj;
                float y1j = byj - 0.5f * bhj, y2j = byj + 0.5f * bhj;
                float aj = bwj * bhj;
                float iw = fmaxf(fminf(x2j, xi2) - fmaxf(x1j, xi1), 0.0f);
                float ih = fmaxf(fminf(y2j, yi2) - fmaxf(y1j, yi1), 0.0f);
                float inter = iw * ih;
                float iou = inter / ((aj + ai) - inter);
                if (iou >= 0.45f) s_obj[j] = 0.0f;
            }
        }
        __syncthreads();
    }

    float v0[8], v1[8], v2[8], v3[8], v4[8], v5[8], v6[8], msk[8];
#pragma unroll
    for (int c = 0; c < 8; ++c) {
        int r = tid + c * K2T;
        if (r < NBOX) {
            const float* row = detb + (int)order[r] * 7;
            float obj = row[0], bx = row[1], by = row[2], bw = row[3];
            float bh = row[4], cid = row[5], prob = row[6];
            bool keep = (r < num_obj) && (s_obj[r] > 0.01f) && (r != num_obj - 1);
            float p = prob * ((prob > 0.1f) ? 1.0f : 0.0f);
            bool fin = keep && (p > 0.01f) && (bw * bw > 0.0004f);
            v0[c] = obj; v1[c] = bx; v2[c] = by; v3[c] = bw; v4[c] = bh;
            v5[c] = cid; v6[c] = p;
            msk[c] = fin ? 1.0f : 0.0f;
        }
    }
    __syncthreads();
#pragma unroll
    for (int c = 0; c < 8; ++c) {
        int r = tid + c * K2T;
        if (r < NBOX) {
            float* o = detb + r * 7;
            o[0] = v0[c] * msk[c]; o[1] = v1[c] * msk[c]; o[2] = v2[c] * msk[c];
            o[3] = v3[c] * msk[c]; o[4] = v4[c] * msk[c]; o[5] = v5[c] * msk[c];
            o[6] = v6[c] * msk[c];
        }
    }
}

extern "C" void kernel_launch(void* const* d_in, const int* in_sizes, int n_in,
                              void* d_out, int out_size, void* d_ws, size_t ws_size,
                              hipStream_t stream)
{
    const float* pred    = (const float*)d_in[0];
    const float* anchors = (const float*)d_in[1];
    float* out = (float*)d_out;

    int total = NBATCH * NBOX;
    int blocks = (total + 255) / 256;
    decode_kernel<<<blocks, 256, 0, stream>>>(pred, anchors, out);

    if (ws_size >= WS_NEEDED) {
        char* ws = (char*)d_ws;
        int*            nobj  = (int*)(ws + WS_NUMOBJ_OFF);
        unsigned short* order = (unsigned short*)(ws + WS_ORDER_OFF);
        float*          sobj  = (float*)(ws + WS_SOBJ_OFF);
        sort_kernel<<<NBATCH, 1024, 0, stream>>>(out, order, sobj, nobj);
        nms3_kernel<<<NBATCH, 64, 0, stream>>>(out, order, sobj, nobj);
        epi_kernel<<<NBATCH, 256, 0, stream>>>(out, order, sobj, nobj);
    } else {
        nms_kernel<<<NBATCH, K2T, 0, stream>>>(out);
    }
}

// Round 5
// 377.922 us; speedup vs baseline: 1.6755x; 1.6755x over previous
//
#include <hip/hip_runtime.h>

#define NUMA 5
#define NCLS 80
#define AL 85          // 80 + 4 + 1
#define HW 361         // 19*19
#define NBOX 1805      // 5*361
#define NBATCH 128
#define NPAD 2048
#define K2T 256
#define MCAP 1024      // register-path cap on num_obj (expected ~902 +/- 21)
#define NCHUNK 16      // MCAP / 64

// ---- d_ws layout (phase-split path) ----
#define WS_NUMOBJ_OFF 0                                  // int32 [128]
#define WS_ORDER_OFF  512                                // u16   [128][2048]
#define WS_SOBJ_OFF   (512 + NBATCH * NPAD * 2)          // f32   [128][2048]
#define WS_NEEDED     ((size_t)(WS_SOBJ_OFF + NBATCH * NPAD * 4))   // ~1.5 MB

// ---------------------------------------------------------------------------
// Kernel 1: decode.  pred [B, 425, 19, 19] -> det [B, 1805, 7] written to out
// ---------------------------------------------------------------------------
__global__ __launch_bounds__(256) void decode_kernel(
    const float* __restrict__ pred,
    const float* __restrict__ anchors,
    float* __restrict__ det)
{
#pragma clang fp contract(off)
    int id = blockIdx.x * blockDim.x + threadIdx.x;
    if (id >= NBATCH * NBOX) return;
    int b = id / NBOX;
    int r = id - b * NBOX;
    int a = r / HW;
    int s = r - a * HW;
    int ci = s % 19;
    int cj = s / 19;

    const float* base = pred + ((size_t)(b * (NUMA * AL) + a * AL) * HW + s);
    float tx  = base[0 * HW];
    float ty  = base[1 * HW];
    float tw  = base[2 * HW];
    float th  = base[3 * HW];
    float obj = base[4 * HW];

    float cmax = base[5 * HW];
    int karg = 0;
#pragma unroll 4
    for (int k = 1; k < NCLS; ++k) {
        float c = base[(5 + k) * HW];
        if (c > cmax) { cmax = c; karg = k; }
    }

    float bx = (tx + (float)ci) / 19.0f;
    float by = (ty + (float)cj) / 19.0f;
    float aw = anchors[2 * a];
    float ah = anchors[2 * a + 1];
    float bw = expf(tw) * (aw / 19.0f);
    float bh = expf(th) * (ah / 19.0f);
    float prob = cmax * obj;
    float cid  = (float)karg;

    float* o = det + (size_t)(b * NBOX + r) * 7;
    o[0] = obj; o[1] = bx; o[2] = by; o[3] = bw; o[4] = bh; o[5] = cid; o[6] = prob;
}

// ---------------------------------------------------------------------------
// Kernel 2: per-image stable bitonic sort (desc by obj). 1024 threads/image.
// ---------------------------------------------------------------------------
__global__ __launch_bounds__(1024) void sort_kernel(
    const float* __restrict__ det,
    unsigned short* __restrict__ order_g,
    float* __restrict__ sobj_g,
    int* __restrict__ nobj_g)
{
    __shared__ unsigned long long keys[NPAD];
    __shared__ int cnt_sh;
    const int b = blockIdx.x;
    const int tid = threadIdx.x;
    const float* detb = det + (size_t)b * NBOX * 7;

    for (int n = tid; n < NPAD; n += 1024) {
        keys[n] = (n < NBOX)
            ? (((unsigned long long)__float_as_uint(detb[n * 7]) << 32)
               | (unsigned long long)(2047 - n))
            : 0ull;
    }
    if (tid == 0) cnt_sh = 0;
    __syncthreads();

    for (unsigned k = 2; k <= NPAD; k <<= 1) {
        for (unsigned j = k >> 1; j > 0; j >>= 1) {
            for (unsigned idx = tid; idx < NPAD; idx += 1024) {
                unsigned ixj = idx ^ j;
                if (ixj > idx) {
                    unsigned long long av = keys[idx], bv = keys[ixj];
                    bool up = ((idx & k) == 0);
                    if (up ? (av < bv) : (av > bv)) { keys[idx] = bv; keys[ixj] = av; }
                }
            }
            __syncthreads();
        }
    }

    int cnt = 0;
    for (int r = tid; r < NBOX; r += 1024) {
        unsigned long long kk = keys[r];
        order_g[b * NPAD + r] = (unsigned short)(2047u - (unsigned)(kk & 0xffffffffu));
        float ob = __uint_as_float((unsigned)(kk >> 32));
        sobj_g[b * NPAD + r] = ob;
        cnt += (ob > 0.5f) ? 1 : 0;
    }
    atomicAdd(&cnt_sh, cnt);
    __syncthreads();
    if (tid == 0) nobj_g[b] = cnt_sh;
}

// ---------------------------------------------------------------------------
// Kernel 3: greedy NMS. ONE wave per image. Per-lane boxes register-resident
// (static indexing only); LDS used only for the dynamic-index accesses
// (broadcast suppressor box, per-chunk diagonal box). Broadcast reads are
// software-pipelined under the off-diagonal VALU work.
// ---------------------------------------------------------------------------
__global__ __launch_bounds__(64, 1) void nms3_kernel(
    const float* __restrict__ det,
    const unsigned short* __restrict__ order_g,
    float* __restrict__ sobj_g,
    const int* __restrict__ nobj_g)
{
#pragma clang fp contract(off)
    __shared__ float4 Qs[MCAP];   // (x1,y1,x2,y2) per sorted rank
    __shared__ float  As[MCAP];
    const int b = blockIdx.x;
    const int lane = threadIdx.x;
    const float* detb = det + (size_t)b * NBOX * 7;
    const unsigned short* ord = order_g + b * NPAD;
    float* sobj = sobj_g + b * NPAD;
    const int num_obj = nobj_g[b];
    const int M = (num_obj < MCAP) ? num_obj : MCAP;

    if (num_obj <= MCAP) {
        // --- load boxes: registers (lane-local, static index) + LDS copy ---
        float4 q[NCHUNK];
        float  ar[NCHUNK];
#pragma unroll
        for (int c = 0; c < NCHUNK; ++c) {
            int r = c * 64 + lane;
            float4 v; float a;
            if (r < M) {
                const float* row = detb + (int)ord[r] * 7;
                float bx = row[1], by = row[2], bw = row[3], bh = row[4];
                v = make_float4(bx - 0.5f * bw, by - 0.5f * bh,
                                bx + 0.5f * bw, by + 0.5f * bh);
                a = bw * bh;
            } else {
                v = make_float4(3e9f, 3e9f, 3.0000001e9f, 3.0000001e9f);
                a = 1.0f;
            }
            q[c] = v; ar[c] = a;
            Qs[r] = v; As[r] = a;
        }
        __syncthreads();

        unsigned rm_bits = 0u;    // bit c = this lane's box in chunk c removed
        for (int cchunk = 0; cchunk * 64 < M; ++cchunk) {
            const int cbase = cchunk * 64;
            const int rem_in = M - cbase;
            const unsigned long long chunkmask =
                (rem_in >= 64) ? ~0ull : ((1ull << rem_in) - 1ull);
            // lane's diagonal-chunk box (dynamic chunk index -> LDS, hoisted)
            float4 qd = Qs[cbase + lane];
            float  ad = As[cbase + lane];
            unsigned long long wc = __ballot((rm_bits >> cchunk) & 1u);
            unsigned long long remaining = chunkmask & ~wc;
            int t = remaining ? (int)__builtin_ctzll(remaining) : 64;
            float4 qi = Qs[cbase + (t < 64 ? t : 0)];
            float  ai = As[cbase + (t < 64 ? t : 0)];

            while (t < 64) {
                // --- diagonal: does box (cbase+t) suppress lane's box? ---
                float iw = fmaxf(fminf(qd.z, qi.z) - fmaxf(qd.x, qi.x), 0.0f);
                float ih = fmaxf(fminf(qd.w, qi.w) - fmaxf(qd.y, qi.y), 0.0f);
                float inter = iw * ih;
                float iou = inter / ((ad + ai) - inter);     // exact ref arith
                bool supp = (iou >= 0.45f) && (lane > t);
                unsigned long long bb = __ballot(supp);
                if (supp) rm_bits |= (1u << cchunk);
                remaining &= ~((t >= 63) ? ~0ull : ((1ull << (t + 1)) - 1ull));
                remaining &= ~bb;
                // --- prefetch next suppressor (hides under off-diag VALU) ---
                int tn = remaining ? (int)__builtin_ctzll(remaining) : 64;
                float4 qn = Qs[cbase + (tn < 64 ? tn : 0)];
                float  an = As[cbase + (tn < 64 ? tn : 0)];
                // --- off-diagonal chunks: register-only, no memory ops ---
#pragma unroll
                for (int c2 = 0; c2 < NCHUNK; ++c2) {
                    if (c2 > cchunk && c2 * 64 < M) {        // wave-uniform
                        float iw2 = fmaxf(fminf(q[c2].z, qi.z) - fmaxf(q[c2].x, qi.x), 0.0f);
                        float ih2 = fmaxf(fminf(q[c2].w, qi.w) - fmaxf(q[c2].y, qi.y), 0.0f);
                        float in2 = iw2 * ih2;
                        float iou2 = in2 / ((ar[c2] + ai) - in2);
                        if (iou2 >= 0.45f) rm_bits |= (1u << c2);
                    }
                }
                qi = qn; ai = an; t = tn;
            }
        }
        // write removals
#pragma unroll
        for (int c2 = 0; c2 < NCHUNK; ++c2) {
            int j = c2 * 64 + lane;
            if (j < M && ((rm_bits >> c2) & 1u)) sobj[j] = 0.0f;
        }
    } else {
        // fallback (num_obj > 1024; statistically unreachable): serial greedy
        for (int i = 0; i < num_obj; ++i) {
            if (sobj[i] > 0.01f) {
                const float* ri = detb + (int)ord[i] * 7;
                float bxi = ri[1], byi = ri[2], bwi = ri[3], bhi = ri[4];
                float xi1 = bxi - 0.5f * bwi, xi2 = bxi + 0.5f * bwi;
                float yi1 = byi - 0.5f * bhi, yi2 = byi + 0.5f * bhi;
                float ai = bwi * bhi;
                for (int j = i + 1 + lane; j < num_obj; j += 64) {
                    const float* rj = detb + (int)ord[j] * 7;
                    float bxj = rj[1], byj = rj[2], bwj = rj[3], bhj = rj[4];
                    float x1j = bxj - 0.5f * bwj, x2j = bxj + 0.5f * bwj;
                    float y1j = byj - 0.5f * bhj, y2j = byj + 0.5f * bhj;
                    float aj = bwj * bhj;
                    float iw = fmaxf(fminf(x2j, xi2) - fmaxf(x1j, xi1), 0.0f);
                    float ih = fmaxf(fminf(y2j, yi2) - fmaxf(y1j, yi1), 0.0f);
                    float inter = iw * ih;
                    float iou = inter / ((aj + ai) - inter);
                    if (iou >= 0.45f) sobj[j] = 0.0f;
                }
            }
            __syncthreads();
        }
    }
}

// ---------------------------------------------------------------------------
// Kernel 4: epilogue. Gather rows in sorted order, apply filters, write det
// in place (all reads before barrier, all writes after).
// ---------------------------------------------------------------------------
__global__ __launch_bounds__(256) void epi_kernel(
    float* __restrict__ det,
    const unsigned short* __restrict__ order_g,
    const float* __restrict__ sobj_g,
    const int* __restrict__ nobj_g)
{
#pragma clang fp contract(off)
    const int b = blockIdx.x;
    const int tid = threadIdx.x;
    float* detb = det + (size_t)b * NBOX * 7;
    const unsigned short* ord = order_g + b * NPAD;
    const float* sobj = sobj_g + b * NPAD;
    const int num_obj = nobj_g[b];

    float v0[8], v1[8], v2[8], v3[8], v4[8], v5[8], v6[8], msk[8];
#pragma unroll
    for (int c = 0; c < 8; ++c) {
        int r = tid + c * 256;
        if (r < NBOX) {
            const float* row = detb + (int)ord[r] * 7;
            float obj = row[0], bx = row[1], by = row[2], bw = row[3];
            float bh = row[4], cid = row[5], prob = row[6];
            bool keep = (r < num_obj) && (sobj[r] > 0.01f) && (r != num_obj - 1);
            float p = prob * ((prob > 0.1f) ? 1.0f : 0.0f);
            bool fin = keep && (p > 0.01f) && (bw * bw > 0.0004f);
            v0[c] = obj; v1[c] = bx; v2[c] = by; v3[c] = bw; v4[c] = bh;
            v5[c] = cid; v6[c] = p;
            msk[c] = fin ? 1.0f : 0.0f;
        }
    }
    __syncthreads();
#pragma unroll
    for (int c = 0; c < 8; ++c) {
        int r = tid + c * 256;
        if (r < NBOX) {
            float* o = detb + r * 7;
            o[0] = v0[c] * msk[c];
            o[1] = v1[c] * msk[c];
            o[2] = v2[c] * msk[c];
            o[3] = v3[c] * msk[c];
            o[4] = v4[c] * msk[c];
            o[5] = v5[c] * msk[c];
            o[6] = v6[c] * msk[c];
        }
    }
}

// ---------------------------------------------------------------------------
// Fallback monolithic kernel (used only if ws_size < WS_NEEDED).
// ---------------------------------------------------------------------------
__global__ __launch_bounds__(K2T, 1) void nms_kernel(float* __restrict__ det)
{
#pragma clang fp contract(off)
    __shared__ alignas(16) union {
        unsigned long long keys[NPAD];
        struct { float4 q[MCAP]; float area[MCAP]; } box;
    } U;
    __shared__ float s_obj[NBOX];
    __shared__ unsigned short order[NBOX];
    __shared__ int num_obj_sh;

    const int b = blockIdx.x;
    const int tid = threadIdx.x;
    float* detb = det + (size_t)b * NBOX * 7;

    for (int n = tid; n < NPAD; n += K2T) {
        if (n < NBOX) {
            unsigned ob = __float_as_uint(detb[n * 7 + 0]);
            U.keys[n] = ((unsigned long long)ob << 32) | (unsigned long long)(2047 - n);
        } else U.keys[n] = 0ull;
    }
    if (tid == 0) num_obj_sh = 0;
    __syncthreads();

    for (unsigned k = 2; k <= NPAD; k <<= 1) {
        for (unsigned j = k >> 1; j > 0; j >>= 1) {
            for (unsigned idx = tid; idx < NPAD; idx += K2T) {
                unsigned ixj = idx ^ j;
                if (ixj > idx) {
                    unsigned long long av = U.keys[idx], bv = U.keys[ixj];
                    bool up = ((idx & k) == 0);
                    if (up ? (av < bv) : (av > bv)) { U.keys[idx] = bv; U.keys[ixj] = av; }
                }
            }
            __syncthreads();
        }
    }

    int cnt = 0;
    for (int r = tid; r < NBOX; r += K2T) {
        unsigned long long kk = U.keys[r];
        order[r] = (unsigned short)(2047u - (unsigned)(kk & 0xffffffffu));
        float ob = __uint_as_float((unsigned)(kk >> 32));
        s_obj[r] = ob;
        cnt += (ob > 0.5f) ? 1 : 0;
    }
    atomicAdd(&num_obj_sh, cnt);
    __syncthreads();
    const int num_obj = num_obj_sh;

    for (int i = 0; i < num_obj; ++i) {
        if (s_obj[i] > 0.01f) {
            const float* ri = detb + (int)order[i] * 7;
            float bxi = ri[1], byi = ri[2], bwi = ri[3], bhi = ri[4];
            float xi1 = bxi - 0.5f * bwi, xi2 = bxi + 0.5f * bwi;
            float yi1 = byi - 0.5f * bhi, yi2 = byi + 0.5f * bhi;
            float ai = bwi * bhi;
            for (int j = i + 1 + tid; j < num_obj; j += K2T) {
                const float* rj = detb + (int)order[j] * 7;
                float bxj = rj[1], byj = rj[2], bwj = rj[3], bhj = rj[4];
                float x1j = bxj - 0.5f * bwj, x2j = bxj + 0.5f * bwj;
                float y1j = byj - 0.5f * bhj, y2j = byj + 0.5f * bhj;
                float aj = bwj * bhj;
                float iw = fmaxf(fminf(x2j, xi2) - fmaxf(x1j, xi1), 0.0f);
                float ih = fmaxf(fminf(y2j, yi2) - fmaxf(y1j, yi1), 0.0f);
                float inter = iw * ih;
                float iou = inter / ((aj + ai) - inter);
                if (iou >= 0.45f) s_obj[j] = 0.0f;
            }
        }
        __syncthreads();
    }

    float v0[8], v1[8], v2[8], v3[8], v4[8], v5[8], v6[8], msk[8];
#pragma unroll
    for (int c = 0; c < 8; ++c) {
        int r = tid + c * K2T;
        if (r < NBOX) {
            const float* row = detb + (int)order[r] * 7;
            float obj = row[0], bx = row[1], by = row[2], bw = row[3];
            float bh = row[4], cid = row[5], prob = row[6];
            bool keep = (r < num_obj) && (s_obj[r] > 0.01f) && (r != num_obj - 1);
            float p = prob * ((prob > 0.1f) ? 1.0f : 0.0f);
            bool fin = keep && (p > 0.01f) && (bw * bw > 0.0004f);
            v0[c] = obj; v1[c] = bx; v2[c] = by; v3[c] = bw; v4[c] = bh;
            v5[c] = cid; v6[c] = p;
            msk[c] = fin ? 1.0f : 0.0f;
        }
    }
    __syncthreads();
#pragma unroll
    for (int c = 0; c < 8; ++c) {
        int r = tid + c * K2T;
        if (r < NBOX) {
            float* o = detb + r * 7;
            o[0] = v0[c] * msk[c]; o[1] = v1[c] * msk[c]; o[2] = v2[c] * msk[c];
            o[3] = v3[c] * msk[c]; o[4] = v4[c] * msk[c]; o[5] = v5[c] * msk[c];
            o[6] = v6[c] * msk[c];
        }
    }
}

extern "C" void kernel_launch(void* const* d_in, const int* in_sizes, int n_in,
                              void* d_out, int out_size, void* d_ws, size_t ws_size,
                              hipStream_t stream)
{
    const float* pred    = (const float*)d_in[0];
    const float* anchors = (const float*)d_in[1];
    float* out = (float*)d_out;

    int total = NBATCH * NBOX;
    int blocks = (total + 255) / 256;
    decode_kernel<<<blocks, 256, 0, stream>>>(pred, anchors, out);

    if (ws_size >= WS_NEEDED) {
        char* ws = (char*)d_ws;
        int*            nobj  = (int*)(ws + WS_NUMOBJ_OFF);
        unsigned short* order = (unsigned short*)(ws + WS_ORDER_OFF);
        float*          sobj  = (float*)(ws + WS_SOBJ_OFF);
        sort_kernel<<<NBATCH, 1024, 0, stream>>>(out, order, sobj, nobj);
        nms3_kernel<<<NBATCH, 64, 0, stream>>>(out, order, sobj, nobj);
        epi_kernel<<<NBATCH, 256, 0, stream>>>(out, order, sobj, nobj);
    } else {
        nms_kernel<<<NBATCH, K2T, 0, stream>>>(out);
    }
}

// Round 6
// 325.464 us; speedup vs baseline: 1.9455x; 1.1612x over previous
//
#include <hip/hip_runtime.h>

#define NUMA 5
#define NCLS 80
#define AL 85          // 80 + 4 + 1
#define HW 361         // 19*19
#define NBOX 1805      // 5*361
#define NBATCH 128
#define NPAD 2048
#define K2T 256
#define MCAP 1024      // register-path cap on num_obj (expected ~902 +/- 21)
#define NCHUNK 16      // MCAP / 64

// ---- d_ws layout (phase-split path) ----
#define WS_NUMOBJ_OFF 0                                  // int32 [128]
#define WS_ORDER_OFF  512                                // u16   [128][2048]
#define WS_SOBJ_OFF   (512 + NBATCH * NPAD * 2)          // f32   [128][2048]
#define WS_NEEDED     ((size_t)(WS_SOBJ_OFF + NBATCH * NPAD * 4))   // ~1.5 MB

__device__ __forceinline__ float bcast_lane(float v, int t) {
    return __uint_as_float(
        (unsigned)__builtin_amdgcn_readlane((int)__float_as_uint(v), t));
}

// ---------------------------------------------------------------------------
// Kernel 1: decode.  pred [B, 425, 19, 19] -> det [B, 1805, 7] written to out
// ---------------------------------------------------------------------------
__global__ __launch_bounds__(256) void decode_kernel(
    const float* __restrict__ pred,
    const float* __restrict__ anchors,
    float* __restrict__ det)
{
#pragma clang fp contract(off)
    int id = blockIdx.x * blockDim.x + threadIdx.x;
    if (id >= NBATCH * NBOX) return;
    int b = id / NBOX;
    int r = id - b * NBOX;
    int a = r / HW;
    int s = r - a * HW;
    int ci = s % 19;
    int cj = s / 19;

    const float* base = pred + ((size_t)(b * (NUMA * AL) + a * AL) * HW + s);
    float tx  = base[0 * HW];
    float ty  = base[1 * HW];
    float tw  = base[2 * HW];
    float th  = base[3 * HW];
    float obj = base[4 * HW];

    float cmax = base[5 * HW];
    int karg = 0;
#pragma unroll 4
    for (int k = 1; k < NCLS; ++k) {
        float c = base[(5 + k) * HW];
        if (c > cmax) { cmax = c; karg = k; }
    }

    float bx = (tx + (float)ci) / 19.0f;
    float by = (ty + (float)cj) / 19.0f;
    float aw = anchors[2 * a];
    float ah = anchors[2 * a + 1];
    float bw = expf(tw) * (aw / 19.0f);
    float bh = expf(th) * (ah / 19.0f);
    float prob = cmax * obj;
    float cid  = (float)karg;

    float* o = det + (size_t)(b * NBOX + r) * 7;
    o[0] = obj; o[1] = bx; o[2] = by; o[3] = bw; o[4] = bh; o[5] = cid; o[6] = prob;
}

// ---------------------------------------------------------------------------
// Kernel 2: per-image stable bitonic sort (desc by obj). 1024 threads/image.
// ---------------------------------------------------------------------------
__global__ __launch_bounds__(1024) void sort_kernel(
    const float* __restrict__ det,
    unsigned short* __restrict__ order_g,
    float* __restrict__ sobj_g,
    int* __restrict__ nobj_g)
{
    __shared__ unsigned long long keys[NPAD];
    __shared__ int cnt_sh;
    const int b = blockIdx.x;
    const int tid = threadIdx.x;
    const float* detb = det + (size_t)b * NBOX * 7;

    for (int n = tid; n < NPAD; n += 1024) {
        keys[n] = (n < NBOX)
            ? (((unsigned long long)__float_as_uint(detb[n * 7]) << 32)
               | (unsigned long long)(2047 - n))
            : 0ull;
    }
    if (tid == 0) cnt_sh = 0;
    __syncthreads();

    for (unsigned k = 2; k <= NPAD; k <<= 1) {
        for (unsigned j = k >> 1; j > 0; j >>= 1) {
            for (unsigned idx = tid; idx < NPAD; idx += 1024) {
                unsigned ixj = idx ^ j;
                if (ixj > idx) {
                    unsigned long long av = keys[idx], bv = keys[ixj];
                    bool up = ((idx & k) == 0);
                    if (up ? (av < bv) : (av > bv)) { keys[idx] = bv; keys[ixj] = av; }
                }
            }
            __syncthreads();
        }
    }

    int cnt = 0;
    for (int r = tid; r < NBOX; r += 1024) {
        unsigned long long kk = keys[r];
        order_g[b * NPAD + r] = (unsigned short)(2047u - (unsigned)(kk & 0xffffffffu));
        float ob = __uint_as_float((unsigned)(kk >> 32));
        sobj_g[b * NPAD + r] = ob;
        cnt += (ob > 0.5f) ? 1 : 0;
    }
    atomicAdd(&cnt_sh, cnt);
    __syncthreads();
    if (tid == 0) nobj_g[b] = cnt_sh;
}

// ---------------------------------------------------------------------------
// Kernel 3: greedy NMS. ONE wave per image. NO LDS: all 1024 boxes live in
// registers (16 chunks x 64 lanes), statically indexed via a fully-unrolled
// outer chunk loop. Suppressor broadcast via v_readlane (wave-uniform index
// from the scalar alive-mask). Sentinel boxes (rank >= M) give iou = 0
// against any real box, so the inner loops need no M guards.
// ---------------------------------------------------------------------------
__global__ __launch_bounds__(64, 1) void nms3_kernel(
    const float* __restrict__ det,
    const unsigned short* __restrict__ order_g,
    float* __restrict__ sobj_g,
    const int* __restrict__ nobj_g)
{
#pragma clang fp contract(off)
    const int b = blockIdx.x;
    const int lane = threadIdx.x;
    const float* detb = det + (size_t)b * NBOX * 7;
    const unsigned short* ord = order_g + b * NPAD;
    float* sobj = sobj_g + b * NPAD;
    const int num_obj = nobj_g[b];
    const int M = (num_obj < MCAP) ? num_obj : MCAP;

    if (num_obj <= MCAP) {
        // --- load lane-local boxes straight into registers (static index) ---
        float4 q[NCHUNK];
        float  ar[NCHUNK];
#pragma unroll
        for (int c = 0; c < NCHUNK; ++c) {
            int r = c * 64 + lane;
            if (r < M) {
                const float* row = detb + (int)ord[r] * 7;
                float bx = row[1], by = row[2], bw = row[3], bh = row[4];
                q[c] = make_float4(bx - 0.5f * bw, by - 0.5f * bh,
                                   bx + 0.5f * bw, by + 0.5f * bh);
                ar[c] = bw * bh;
            } else {
                q[c] = make_float4(3e9f, 3e9f, 3.0000001e9f, 3.0000001e9f);
                ar[c] = 1.0f;
            }
        }

        unsigned rm_bits = 0u;    // bit c = this lane's box in chunk c removed
#pragma unroll
        for (int cchunk = 0; cchunk < NCHUNK; ++cchunk) {
            if (cchunk * 64 < M) {                      // wave-uniform
                const int rem_in = M - cchunk * 64;
                const unsigned long long chunkmask =
                    (rem_in >= 64) ? ~0ull : ((1ull << rem_in) - 1ull);
                unsigned long long wc = __ballot((rm_bits >> cchunk) & 1u);
                unsigned long long remaining = chunkmask & ~wc;
                while (remaining) {
                    int t = (int)__builtin_ctzll(remaining);  // SGPR, uniform
                    // broadcast suppressor box from lane t (registers only)
                    float xi1 = bcast_lane(q[cchunk].x, t);
                    float yi1 = bcast_lane(q[cchunk].y, t);
                    float xi2 = bcast_lane(q[cchunk].z, t);
                    float yi2 = bcast_lane(q[cchunk].w, t);
                    float ai  = bcast_lane(ar[cchunk],  t);
                    // --- diagonal: does box t suppress lane's chunk box? ---
                    float iw = fmaxf(fminf(q[cchunk].z, xi2) - fmaxf(q[cchunk].x, xi1), 0.0f);
                    float ih = fmaxf(fminf(q[cchunk].w, yi2) - fmaxf(q[cchunk].y, yi1), 0.0f);
                    float inter = iw * ih;
                    float iou = inter / ((ar[cchunk] + ai) - inter);  // exact ref arith
                    bool supp = (iou >= 0.45f) && (lane > t);
                    unsigned long long bb = __ballot(supp);
                    rm_bits |= supp ? (1u << cchunk) : 0u;
                    remaining &= ~bb;
                    remaining &= ~((t >= 63) ? ~0ull : ((1ull << (t + 1)) - 1ull));
                    // --- off-diagonal chunks: register-only, branchless ---
#pragma unroll
                    for (int c2 = cchunk + 1; c2 < NCHUNK; ++c2) {
                        float iw2 = fmaxf(fminf(q[c2].z, xi2) - fmaxf(q[c2].x, xi1), 0.0f);
                        float ih2 = fmaxf(fminf(q[c2].w, yi2) - fmaxf(q[c2].y, yi1), 0.0f);
                        float in2 = iw2 * ih2;
                        float iou2 = in2 / ((ar[c2] + ai) - in2);
                        rm_bits |= (iou2 >= 0.45f) ? (1u << c2) : 0u;
                    }
                }
            }
        }
        // --- write removals ---
#pragma unroll
        for (int c2 = 0; c2 < NCHUNK; ++c2) {
            int j = c2 * 64 + lane;
            if (j < M && ((rm_bits >> c2) & 1u)) sobj[j] = 0.0f;
        }
    } else {
        // fallback (num_obj > 1024; statistically unreachable): serial greedy
        for (int i = 0; i < num_obj; ++i) {
            if (sobj[i] > 0.01f) {
                const float* ri = detb + (int)ord[i] * 7;
                float bxi = ri[1], byi = ri[2], bwi = ri[3], bhi = ri[4];
                float xi1 = bxi - 0.5f * bwi, xi2 = bxi + 0.5f * bwi;
                float yi1 = byi - 0.5f * bhi, yi2 = byi + 0.5f * bhi;
                float ai = bwi * bhi;
                for (int j = i + 1 + lane; j < num_obj; j += 64) {
                    const float* rj = detb + (int)ord[j] * 7;
                    float bxj = rj[1], byj = rj[2], bwj = rj[3], bhj = rj[4];
                    float x1j = bxj - 0.5f * bwj, x2j = bxj + 0.5f * bwj;
                    float y1j = byj - 0.5f * bhj, y2j = byj + 0.5f * bhj;
                    float aj = bwj * bhj;
                    float iw = fmaxf(fminf(x2j, xi2) - fmaxf(x1j, xi1), 0.0f);
                    float ih = fmaxf(fminf(y2j, yi2) - fmaxf(y1j, yi1), 0.0f);
                    float inter = iw * ih;
                    float iou = inter / ((aj + ai) - inter);
                    if (iou >= 0.45f) sobj[j] = 0.0f;
                }
            }
            __syncthreads();
        }
    }
}

// ---------------------------------------------------------------------------
// Kernel 4: epilogue. Gather rows in sorted order, apply filters, write det
// in place (all reads before barrier, all writes after).
// ---------------------------------------------------------------------------
__global__ __launch_bounds__(256) void epi_kernel(
    float* __restrict__ det,
    const unsigned short* __restrict__ order_g,
    const float* __restrict__ sobj_g,
    const int* __restrict__ nobj_g)
{
#pragma clang fp contract(off)
    const int b = blockIdx.x;
    const int tid = threadIdx.x;
    float* detb = det + (size_t)b * NBOX * 7;
    const unsigned short* ord = order_g + b * NPAD;
    const float* sobj = sobj_g + b * NPAD;
    const int num_obj = nobj_g[b];

    float v0[8], v1[8], v2[8], v3[8], v4[8], v5[8], v6[8], msk[8];
#pragma unroll
    for (int c = 0; c < 8; ++c) {
        int r = tid + c * 256;
        if (r < NBOX) {
            const float* row = detb + (int)ord[r] * 7;
            float obj = row[0], bx = row[1], by = row[2], bw = row[3];
            float bh = row[4], cid = row[5], prob = row[6];
            bool keep = (r < num_obj) && (sobj[r] > 0.01f) && (r != num_obj - 1);
            float p = prob * ((prob > 0.1f) ? 1.0f : 0.0f);
            bool fin = keep && (p > 0.01f) && (bw * bw > 0.0004f);
            v0[c] = obj; v1[c] = bx; v2[c] = by; v3[c] = bw; v4[c] = bh;
            v5[c] = cid; v6[c] = p;
            msk[c] = fin ? 1.0f : 0.0f;
        }
    }
    __syncthreads();
#pragma unroll
    for (int c = 0; c < 8; ++c) {
        int r = tid + c * 256;
        if (r < NBOX) {
            float* o = detb + r * 7;
            o[0] = v0[c] * msk[c];
            o[1] = v1[c] * msk[c];
            o[2] = v2[c] * msk[c];
            o[3] = v3[c] * msk[c];
            o[4] = v4[c] * msk[c];
            o[5] = v5[c] * msk[c];
            o[6] = v6[c] * msk[c];
        }
    }
}

// ---------------------------------------------------------------------------
// Fallback monolithic kernel (used only if ws_size < WS_NEEDED).
// ---------------------------------------------------------------------------
__global__ __launch_bounds__(K2T, 1) void nms_kernel(float* __restrict__ det)
{
#pragma clang fp contract(off)
    __shared__ alignas(16) union {
        unsigned long long keys[NPAD];
        struct { float4 q[MCAP]; float area[MCAP]; } box;
    } U;
    __shared__ float s_obj[NBOX];
    __shared__ unsigned short order[NBOX];
    __shared__ int num_obj_sh;

    const int b = blockIdx.x;
    const int tid = threadIdx.x;
    float* detb = det + (size_t)b * NBOX * 7;

    for (int n = tid; n < NPAD; n += K2T) {
        if (n < NBOX) {
            unsigned ob = __float_as_uint(detb[n * 7 + 0]);
            U.keys[n] = ((unsigned long long)ob << 32) | (unsigned long long)(2047 - n);
        } else U.keys[n] = 0ull;
    }
    if (tid == 0) num_obj_sh = 0;
    __syncthreads();

    for (unsigned k = 2; k <= NPAD; k <<= 1) {
        for (unsigned j = k >> 1; j > 0; j >>= 1) {
            for (unsigned idx = tid; idx < NPAD; idx += K2T) {
                unsigned ixj = idx ^ j;
                if (ixj > idx) {
                    unsigned long long av = U.keys[idx], bv = U.keys[ixj];
                    bool up = ((idx & k) == 0);
                    if (up ? (av < bv) : (av > bv)) { U.keys[idx] = bv; U.keys[ixj] = av; }
                }
            }
            __syncthreads();
        }
    }

    int cnt = 0;
    for (int r = tid; r < NBOX; r += K2T) {
        unsigned long long kk = U.keys[r];
        order[r] = (unsigned short)(2047u - (unsigned)(kk & 0xffffffffu));
        float ob = __uint_as_float((unsigned)(kk >> 32));
        s_obj[r] = ob;
        cnt += (ob > 0.5f) ? 1 : 0;
    }
    atomicAdd(&num_obj_sh, cnt);
    __syncthreads();
    const int num_obj = num_obj_sh;

    for (int i = 0; i < num_obj; ++i) {
        if (s_obj[i] > 0.01f) {
            const float* ri = detb + (int)order[i] * 7;
            float bxi = ri[1], byi = ri[2], bwi = ri[3], bhi = ri[4];
            float xi1 = bxi - 0.5f * bwi, xi2 = bxi + 0.5f * bwi;
            float yi1 = byi - 0.5f * bhi, yi2 = byi + 0.5f * bhi;
            float ai = bwi * bhi;
            for (int j = i + 1 + tid; j < num_obj; j += K2T) {
                const float* rj = detb + (int)order[j] * 7;
                float bxj = rj[1], byj = rj[2], bwj = rj[3], bhj = rj[4];
                float x1j = bxj - 0.5f * bwj, x2j = bxj + 0.5f * bwj;
                float y1j = byj - 0.5f * bhj, y2j = byj + 0.5f * bhj;
                float aj = bwj * bhj;
                float iw = fmaxf(fminf(x2j, xi2) - fmaxf(x1j, xi1), 0.0f);
                float ih = fmaxf(fminf(y2j, yi2) - fmaxf(y1j, yi1), 0.0f);
                float inter = iw * ih;
                float iou = inter / ((aj + ai) - inter);
                if (iou >= 0.45f) s_obj[j] = 0.0f;
            }
        }
        __syncthreads();
    }

    float v0[8], v1[8], v2[8], v3[8], v4[8], v5[8], v6[8], msk[8];
#pragma unroll
    for (int c = 0; c < 8; ++c) {
        int r = tid + c * K2T;
        if (r < NBOX) {
            const float* row = detb + (int)order[r] * 7;
            float obj = row[0], bx = row[1], by = row[2], bw = row[3];
            float bh = row[4], cid = row[5], prob = row[6];
            bool keep = (r < num_obj) && (s_obj[r] > 0.01f) && (r != num_obj - 1);
            float p = prob * ((prob > 0.1f) ? 1.0f : 0.0f);
            bool fin = keep && (p > 0.01f) && (bw * bw > 0.0004f);
            v0[c] = obj; v1[c] = bx; v2[c] = by; v3[c] = bw; v4[c] = bh;
            v5[c] = cid; v6[c] = p;
            msk[c] = fin ? 1.0f : 0.0f;
        }
    }
    __syncthreads();
#pragma unroll
    for (int c = 0; c < 8; ++c) {
        int r = tid + c * K2T;
        if (r < NBOX) {
            float* o = detb + r * 7;
            o[0] = v0[c] * msk[c]; o[1] = v1[c] * msk[c]; o[2] = v2[c] * msk[c];
            o[3] = v3[c] * msk[c]; o[4] = v4[c] * msk[c]; o[5] = v5[c] * msk[c];
            o[6] = v6[c] * msk[c];
        }
    }
}

extern "C" void kernel_launch(void* const* d_in, const int* in_sizes, int n_in,
                              void* d_out, int out_size, void* d_ws, size_t ws_size,
                              hipStream_t stream)
{
    const float* pred    = (const float*)d_in[0];
    const float* anchors = (const float*)d_in[1];
    float* out = (float*)d_out;

    int total = NBATCH * NBOX;
    int blocks = (total + 255) / 256;
    decode_kernel<<<blocks, 256, 0, stream>>>(pred, anchors, out);

    if (ws_size >= WS_NEEDED) {
        char* ws = (char*)d_ws;
        int*            nobj  = (int*)(ws + WS_NUMOBJ_OFF);
        unsigned short* order = (unsigned short*)(ws + WS_ORDER_OFF);
        float*          sobj  = (float*)(ws + WS_SOBJ_OFF);
        sort_kernel<<<NBATCH, 1024, 0, stream>>>(out, order, sobj, nobj);
        nms3_kernel<<<NBATCH, 64, 0, stream>>>(out, order, sobj, nobj);
        epi_kernel<<<NBATCH, 256, 0, stream>>>(out, order, sobj, nobj);
    } else {
        nms_kernel<<<NBATCH, K2T, 0, stream>>>(out);
    }
}